// Round 9
// baseline (126.182 us; speedup 1.0000x reference)
//
#include <hip/hip_runtime.h>

// One wave (64 lanes) per batch element. State: 1024 complex amps = 16/lane
// as packed float2. s = lane*16 + r; qubit q <-> s-bit (9-q). No LDS staging.
//
// R12: CNOTs folded into gates by GF(2) conjugation (126us bench / 55.7us disp).
// R16 WIN (117.8us / 47.5us): gate complex MAC as v_pk_mul/v_pk_fma VOP3P.
// R17 NEUTRAL (ds batch re-serialized). R18 REGRESS (pair-swap hybrid).
// R19 REGRESS (2 elems/wave: ILP didn't replace lost TLP; 53us).
// R20: runtime 47.5 = VALU 25.6 + LDS 19 (SUM, not max) -> waves are
//   PHASE-LOCKED: identical gate sequence means all 16 waves/CU hit the
//   shared LDS unit together, then all do VALU together. Fix: gates within
//   a layer commute (distinct qubits, same frame) -> rotate each layer's
//   gate order by (blockIdx + 3*wave) % 10 (wave-uniform switch). Plus
//   masks 7/15 become single-DPP (row_half_mirror/row_mirror).

typedef float v2 __attribute__((ext_vector_type(2)));

// ===== compile-time GF(2) linear algebra on 10-bit indices =====
struct M10 { unsigned row[10]; };
constexpr M10 mident() { M10 m{}; for (int i=0;i<10;++i) m.row[i]=1u<<i; return m; }
constexpr M10 mmul(M10 A, M10 B) {   // (A*B)s = A(Bs); row_i(AB) = xor_{j in row_i(A)} row_j(B)
  M10 C{};
  for (int i=0;i<10;++i){ unsigned x=0; for (int j=0;j<10;++j) if ((A.row[i]>>j)&1u) x ^= B.row[j]; C.row[i]=x; }
  return C;
}
constexpr M10 cnotT(int ctrl, int rng) {     // s -> s ^ s_cb*e_tb  (self-inverse)
  const int tgt = (ctrl + rng) % 10;
  const int cb = 9 - ctrl, tb = 9 - tgt;
  M10 m = mident(); m.row[tb] = (1u<<tb)|(1u<<cb); return m;
}
// block applied ctrl=0..9 sequentially: psi_out(s) = psi_in(T0*T1*...*T9 s)
constexpr M10 blockPinv(int rng) { M10 m = cnotT(0,rng); for (int c=1;c<10;++c) m = mmul(m, cnotT(c,rng)); return m; }
constexpr M10 blockP(int rng)    { M10 m = cnotT(9,rng); for (int c=8;c>=0;--c) m = mmul(m, cnotT(c,rng)); return m; }
constexpr unsigned mcol(M10 A, int c) { unsigned x=0; for (int i=0;i<10;++i) x |= ((A.row[i]>>c)&1u)<<i; return x; }
constexpr int par(unsigned x){ int p=0; for (int i=0;i<10;++i) p ^= (int)((x>>i)&1u); return p; }
constexpr int topbit4(int x){ int b=0; for (int i=1;i<4;++i) if (x>>i) b=i; return 1<<b; }

constexpr M10 Q1  = blockP(1);
constexpr M10 Q1i = blockPinv(1);
constexpr M10 Q2  = mmul(blockP(2), Q1);
constexpr M10 Q2i = mmul(Q1i, blockPinv(2));
constexpr M10 Q3  = mmul(blockP(3), Q2);

static_assert(mmul(Q1, Q1i).row[0]==1u && mmul(Q1,Q1i).row[9]==(1u<<9), "inv1");
static_assert(mmul(Q2, Q2i).row[0]==1u && mmul(Q2,Q2i).row[7]==(1u<<7), "inv2");
static_assert(par(mcol(Q1i,0)&Q1.row[0]) && par(mcol(Q1i,5)&Q1.row[5]) && par(mcol(Q1i,9)&Q1.row[9]), "dual1");
static_assert(par(mcol(Q2i,0)&Q2.row[0]) && par(mcol(Q2i,4)&Q2.row[4]) && par(mcol(Q2i,9)&Q2.row[9]), "dual2");

// ===== cross-lane xor (DPP cheap cases incl 7/15, ds_swizzle <=31, bpermute >=32) =====
template<int CTRL>
__device__ __forceinline__ float dppf(float v) {
  return __int_as_float(__builtin_amdgcn_update_dpp(
      0, __float_as_int(v), CTRL, 0xF, 0xF, true));
}

template<int MASK>
__device__ __forceinline__ float xany(float v, int baddr) {
  constexpr int QC[4] = {0, 0xB1, 0x4E, 0x1B};
  if constexpr (MASK == 0) return v;
  else if constexpr (MASK <= 3) return dppf<QC[MASK]>(v);
  else if constexpr (MASK == 4) return dppf<0x141>(dppf<0x1B>(v));     // xor7 o xor3
  else if constexpr (MASK == 7) return dppf<0x141>(v);                 // row_half_mirror
  else if constexpr (MASK == 8) return dppf<0x128>(v);                 // row_ror:8
  else if constexpr (MASK >= 9 && MASK <= 11) return dppf<QC[MASK&3]>(dppf<0x128>(v));
  else if constexpr (MASK == 15) return dppf<0x140>(v);                // row_mirror
  else if constexpr (MASK < 32) return __int_as_float(__builtin_amdgcn_ds_swizzle(__float_as_int(v), (MASK<<10)|0x1F));
  else return __int_as_float(__builtin_amdgcn_ds_bpermute(baddr, __float_as_int(v)));
}
template<int MASK>
__device__ __forceinline__ v2 xany2(v2 v, int baddr) {
  v2 r; r.x = xany<MASK>(v.x, baddr); r.y = xany<MASK>(v.y, baddr); return r;
}

// pow2-only xor (reductions)
template<int LM>
__device__ __forceinline__ float xshfl(float v) {
  if constexpr (LM == 1) return dppf<0xB1>(v);
  else if constexpr (LM == 2) return dppf<0x4E>(v);
  else if constexpr (LM == 4) return dppf<0x141>(dppf<0x1B>(v));
  else if constexpr (LM == 8) return dppf<0x128>(v);
  else if constexpr (LM == 16) return __int_as_float(__builtin_amdgcn_ds_swizzle(__float_as_int(v), 0x401F));
  else return __shfl_xor(v, 32);
}

// multi-value funnel stage: NP pairs (i, i+NP) across lane bit B
template<int B, int NP>
__device__ __forceinline__ void fstage(float* p, int lane) {
  #pragma unroll
  for (int i = 0; i < NP; ++i) {
    const float send = (lane & B) ? p[i] : p[i + NP];
    const float recv = xshfl<B>(send);
    const float keep = (lane & B) ? p[i + NP] : p[i];
    p[i] = keep + recv;
  }
}
constexpr int holder_lane45(int v) {
  const int a = v >= 24; int r = v - 24 * a;
  const int b = r >= 12; r -= 12 * b;
  const int c = r >= 6;  r -= 6 * c;
  const int d = r >= 3;  r -= 3 * d;
  const int e = r >= 2;  r -= 2 * e;
  return a | (b << 1) | (c << 2) | (d << 3) | (e << 4) | (r << 5);
}
constexpr int holder_lane10(int v) {
  const int a = v >= 5; int r = v - 5 * a;
  const int b = r >= 3; r -= 3 * b;
  const int c = r >= 2; r -= 2 * c;
  return a | (b << 1) | (c << 2) | (r << 3);
}

__device__ __forceinline__ float rfl(float x) {
  return __int_as_float(__builtin_amdgcn_readfirstlane(__float_as_int(x)));
}
#define RLg(g_, x_) __int_as_float(__builtin_amdgcn_readlane(__float_as_int(x_), (g_)))

__device__ __forceinline__ float fast_tanh(float x) {
  return 1.0f - 2.0f / (__expf(2.0f * x) + 1.0f);
}
__device__ __forceinline__ v2 sneg(v2 a) {       // i*a: (re,im)->(-im,re)
  v2 r; r.x = -a.y; r.y = a.x; return r;
}

// ===== packed complex MAC core: 4 VOP3P ops per amplitude (R16, verified) =====
__device__ __forceinline__ v2 gate_upd_p(v2 a, v2 p, v2 ar2, v2 ai2, v2 br2, v2 bi2) {
  v2 acc;
  asm("v_pk_mul_f32 %0, %1, %2" : "=v"(acc) : "v"(ar2), "v"(a));
  asm("v_pk_fma_f32 %0, %1, %2, %0 op_sel:[1,0,0] op_sel_hi:[0,1,1] neg_lo:[1,0,0]"
      : "+v"(acc) : "v"(a), "v"(ai2));
  asm("v_pk_fma_f32 %0, %1, %2, %0"
      : "+v"(acc) : "v"(p), "v"(br2));
  asm("v_pk_fma_f32 %0, %1, %2, %0 op_sel:[1,0,0] op_sel_hi:[0,1,1] neg_lo:[1,0,0]"
      : "+v"(acc) : "v"(p), "v"(bi2));
  return acc;
}
__device__ __forceinline__ v2 gate_upd_m(v2 a, v2 p, v2 ar2, v2 ai2, v2 br2, v2 bi2) {
  v2 acc;
  asm("v_pk_mul_f32 %0, %1, %2" : "=v"(acc) : "v"(ar2), "v"(a));
  asm("v_pk_fma_f32 %0, %1, %2, %0 op_sel:[1,0,0] op_sel_hi:[0,1,1] neg_hi:[1,0,0]"
      : "+v"(acc) : "v"(a), "v"(ai2));
  asm("v_pk_fma_f32 %0, %1, %2, %0 neg_lo:[1,0,0] neg_hi:[1,0,0]"
      : "+v"(acc) : "v"(p), "v"(br2));
  asm("v_pk_fma_f32 %0, %1, %2, %0 op_sel:[1,0,0] op_sel_hi:[0,1,1] neg_lo:[1,0,0]"
      : "+v"(acc) : "v"(p), "v"(bi2));
  return acc;
}

// ===== general conjugated gate (R17 structure) =====
template<int M, int V>
__device__ __forceinline__ void gate_g(v2 (&st)[16], int lane,
                                       float ar, float ai, float br, float bi) {
  constexpr int MR = M & 15, ML = (M >> 4) & 63;
  constexpr int VR = V & 15, VL = (V >> 4) & 63;
  bool hl = false;
  if constexpr (VL != 0) hl = (__builtin_popcount(lane & VL) & 1) != 0;
  const float aiX = hl ? -ai : ai;
  const float brX = hl ? -br : br;
  v2 ar2; ar2.x = ar;  ar2.y = ar;
  v2 ai2; ai2.x = aiX; ai2.y = aiX;
  v2 br2; br2.x = brX; br2.y = brX;
  v2 bi2; bi2.x = bi;  bi2.y = bi;
  int baddr = 0;
  if constexpr (ML >= 32) baddr = (lane ^ ML) << 2;
  if constexpr (ML >= 12) {
    v2 pf[16];
    #pragma unroll
    for (int r = 0; r < 16; ++r) pf[r] = xany2<ML>(st[r ^ MR], baddr);
    #pragma unroll
    for (int r = 0; r < 16; ++r) {
      if ((__builtin_popcount(r & VR) & 1) == 0)
        st[r] = gate_upd_p(st[r], pf[r], ar2, ai2, br2, bi2);
      else
        st[r] = gate_upd_m(st[r], pf[r], ar2, ai2, br2, bi2);
    }
  } else if constexpr (MR == 0) {
    #pragma unroll
    for (int r = 0; r < 16; ++r) {
      const v2 p = xany2<ML>(st[r], baddr);
      const v2 a = st[r];
      if ((__builtin_popcount(r & VR) & 1) == 0)
        st[r] = gate_upd_p(a, p, ar2, ai2, br2, bi2);
      else
        st[r] = gate_upd_m(a, p, ar2, ai2, br2, bi2);
    }
  } else {
    constexpr int HB = topbit4(MR);
    #pragma unroll
    for (int r = 0; r < 16; ++r) {
      if ((r & HB) == 0) {
        const int r1 = r ^ MR;
        v2 pa, pb;
        if constexpr (ML == 0) { pa = st[r1]; pb = st[r]; }
        else { pa = xany2<ML>(st[r1], baddr); pb = xany2<ML>(st[r], baddr); }
        const v2 a = st[r], b = st[r1];
        if ((__builtin_popcount(r & VR) & 1) == 0)
          st[r] = gate_upd_p(a, pa, ar2, ai2, br2, bi2);
        else
          st[r] = gate_upd_m(a, pa, ar2, ai2, br2, bi2);
        if ((__builtin_popcount(r1 & VR) & 1) == 0)
          st[r1] = gate_upd_p(b, pb, ar2, ai2, br2, bi2);
        else
          st[r1] = gate_upd_m(b, pb, ar2, ai2, br2, bi2);
      }
    }
  }
}

// half_ang decomposition (unchanged): C(lane) + d[j]*z_j(r) + e[ij]*z_i(r)z_j(r)
template<int I, int J>
__device__ __forceinline__ void pair_accum(float t, int lane, float& Cc,
                                           float (&dcf)[4], float (&ecf)[6]) {
  if constexpr (J <= 5) {
    const bool diff = (((lane >> (5 - I)) ^ (lane >> (5 - J))) & 1) != 0;
    Cc += diff ? -t : t;
  } else if constexpr (I <= 5) {
    const bool b = ((lane >> (5 - I)) & 1) != 0;
    dcf[J - 6] += b ? -t : t;
  } else {
    constexpr int eb = (I == 6) ? 0 : (I == 7) ? 3 : 5;
    ecf[eb + (J - I - 1)] = t;
  }
}
#define PACC(v_, i_, j_) pair_accum<i_, j_>(RLg(holder_lane45(v_), tl), lane, Cc, dcoef, ecoef);

#define GATE0(g_, q_) gate_g<(1<<(9-(q_))), (1<<(9-(q_)))>(st, lane, \
    RLg(g_,Mr00), RLg(g_,Mi00), RLg(g_,Mr01), RLg(g_,Mi01));
#define GATE1(g_, q_) gate_g<(int)mcol(Q1i,9-(q_)), (int)Q1.row[9-(q_)]>(st, lane, \
    RLg(g_,Mr00), RLg(g_,Mi00), RLg(g_,Mr01), RLg(g_,Mi01));
#define GATE2(g_, q_) gate_g<(int)mcol(Q2i,9-(q_)), (int)Q2.row[9-(q_)]>(st, lane, \
    RLg(g_,Mr00), RLg(g_,Mi00), RLg(g_,Mr01), RLg(g_,Mi01));

extern "C" __global__ void __launch_bounds__(256, 2)
qhl_kernel(const float* __restrict__ c_kt, const float* __restrict__ dc_kt,
           const float* __restrict__ vw,  const float* __restrict__ w_proj,
           const float* __restrict__ b_proj, const float* __restrict__ log_alpha,
           float* __restrict__ out) {
  const int wave = threadIdx.x >> 6;
  const int lane = threadIdx.x & 63;
  const int bid  = blockIdx.x * 4 + wave;

  const float* c   = c_kt  + (size_t)bid * 1280;
  const float* dcp = dc_kt + (size_t)bid * 1280;

  // ---- per-lane gate-matrix precompute: lane g -> gate (l=g/10, q=g%10)
  float Mr00, Mi00, Mr01, Mi01;
  {
    const int g = lane < 30 ? lane : 0;
    const int l = g / 10, q = g - l * 10;
    const float w0 = vw[g*3+0], w1 = vw[g*3+1], w2 = vw[g*3+2];
    float cY, sY; __sincosf(0.5f*w1, &sY, &cY);
    float ca, sa; __sincosf(0.5f*(w0+w2), &sa, &ca);
    float cb, sb; __sincosf(0.5f*(w0-w2), &sb, &cb);
    const float r00r =  cY*ca, r00i = -cY*sa, r01r = -sY*cb, r01i = -sY*sb;
    if (l == 0) {
      Mr00 = r00r; Mi00 = r00i; Mr01 = r01r; Mi01 = r01i;
    } else {
      const float thq = c[1270 + q], phq = dcp[1270 + q];
      float cy, sy; __sincosf(0.25f * thq, &sy, &cy);
      float cz, sz; __sincosf(0.25f * phq, &sz, &cz);
      const float e00r =  cy*cz, e00i = -cy*sz, e01r = -sy*cz, e01i =  sy*sz;
      const float e10r =  sy*cz, e10i =  sy*sz, e11r =  cy*cz, e11i =  cy*sz;
      Mr00 = r00r*e00r - r00i*e00i + r01r*e10r - r01i*e10i;
      Mi00 = r00r*e00i + r00i*e00r + r01r*e10i + r01i*e10r;
      Mr01 = r00r*e01r - r00i*e01i + r01r*e11r - r01i*e11i;
      Mi01 = r00r*e01i + r00i*e01r + r01r*e11i + r01i*e11r;
    }
  }

  // ---- correlation rows packed as (t=lane, t=lane+64) float2 pairs ----
  v2 ym[10];
  {
    const float2* c0 = (const float2*)(c   + lane * 10);
    const float2* d0 = (const float2*)(dcp + lane * 10);
    const float2* c1 = (const float2*)(c   + (lane + 64) * 10);
    const float2* d1 = (const float2*)(dcp + (lane + 64) * 10);
    #pragma unroll
    for (int k = 0; k < 5; ++k) {
      const float2 a0 = c0[k], b0 = d0[k], a1 = c1[k], b1 = d1[k];
      ym[2*k].x   = a0.x + 0.5f * b0.x;  ym[2*k].y   = a1.x + 0.5f * b1.x;
      ym[2*k+1].x = a0.y + 0.5f * b0.y;  ym[2*k+1].y = a1.y + 0.5f * b1.y;
    }
  }

  // ---- row stats via 10-value funnels ----
  {
    float mb[6];
    float m10a[10];
    #pragma unroll
    for (int k = 0; k < 10; ++k) m10a[k] = ym[k].x + ym[k].y;
    #pragma unroll
    for (int i = 0; i < 5; ++i) {
      const float send = (lane & 1) ? m10a[i] : m10a[i + 5];
      const float recv = xshfl<1>(send);
      const float keep = (lane & 1) ? m10a[i + 5] : m10a[i];
      mb[i] = keep + recv;
    }
    mb[5] = 0.0f;
    fstage<2, 3>(mb, lane);
    mb[3] = 0.0f;
    fstage<4, 2>(mb, lane);
    fstage<8, 1>(mb, lane);
    mb[0] += xshfl<16>(mb[0]);
    mb[0] += xshfl<32>(mb[0]);
    mb[0] *= (1.0f / 128.0f);
    #pragma unroll
    for (int k = 0; k < 10; ++k) {
      const float mk = RLg(holder_lane10(k), mb[0]);
      ym[k].x -= mk; ym[k].y -= mk;
    }
    float s10[10];
    #pragma unroll
    for (int k = 0; k < 10; ++k) { const v2 sq = ym[k] * ym[k]; s10[k] = sq.x + sq.y; }
    #pragma unroll
    for (int i = 0; i < 5; ++i) {
      const float send = (lane & 1) ? s10[i] : s10[i + 5];
      const float recv = xshfl<1>(send);
      const float keep = (lane & 1) ? s10[i + 5] : s10[i];
      mb[i] = keep + recv;
    }
    mb[5] = 0.0f;
    fstage<2, 3>(mb, lane);
    mb[3] = 0.0f;
    fstage<4, 2>(mb, lane);
    fstage<8, 1>(mb, lane);
    mb[0] += xshfl<16>(mb[0]);
    mb[0] += xshfl<32>(mb[0]);
    const float rsv = fminf(__builtin_amdgcn_rsqf(mb[0] * (1.0f / 127.0f)), 1e8f);
    #pragma unroll
    for (int k = 0; k < 10; ++k) {
      const float rk = RLg(holder_lane10(k), rsv);
      ym[k].x *= rk; ym[k].y *= rk;
    }
  }

  // ---- 45 pair dots via one 48-slot funnel; tanh lane-parallel ----
  const float expA = rfl(__expf(log_alpha[0]));
  float Cc = 0.0f, dcoef[4] = {0, 0, 0, 0}, ecoef[6];
  float tl;
  {
    constexpr int PI_[45] = {0,0,0,0,0,0,0,0,0, 1,1,1,1,1,1,1,1, 2,2,2,2,2,2,2,
                             3,3,3,3,3,3, 4,4,4,4,4, 5,5,5,5, 6,6,6, 7,7, 8};
    constexpr int PJ_[45] = {1,2,3,4,5,6,7,8,9, 2,3,4,5,6,7,8,9, 3,4,5,6,7,8,9,
                             4,5,6,7,8,9, 5,6,7,8,9, 6,7,8,9, 7,8,9, 8,9, 9};
    float p[48];
    #pragma unroll
    for (int v = 0; v < 45; ++v) {
      const v2 pr = ym[PI_[v]] * ym[PJ_[v]];
      p[v] = pr.x + pr.y;
    }
    p[45] = 0.0f; p[46] = 0.0f; p[47] = 0.0f;
    fstage<1, 24>(p, lane);
    fstage<2, 12>(p, lane);
    fstage<4, 6>(p, lane);
    fstage<8, 3>(p, lane);
    p[3] = 0.0f;
    fstage<16, 2>(p, lane);
    fstage<32, 1>(p, lane);
    const float sc = expA * (1.0f / 127.0f);
    tl = -1.5707963267948966f * fast_tanh(p[0] * sc);
  }
  PACC(0,0,1) PACC(1,0,2) PACC(2,0,3) PACC(3,0,4) PACC(4,0,5) PACC(5,0,6) PACC(6,0,7) PACC(7,0,8) PACC(8,0,9)
  PACC(9,1,2) PACC(10,1,3) PACC(11,1,4) PACC(12,1,5) PACC(13,1,6) PACC(14,1,7) PACC(15,1,8) PACC(16,1,9)
  PACC(17,2,3) PACC(18,2,4) PACC(19,2,5) PACC(20,2,6) PACC(21,2,7) PACC(22,2,8) PACC(23,2,9)
  PACC(24,3,4) PACC(25,3,5) PACC(26,3,6) PACC(27,3,7) PACC(28,3,8) PACC(29,3,9)
  PACC(30,4,5) PACC(31,4,6) PACC(32,4,7) PACC(33,4,8) PACC(34,4,9)
  PACC(35,5,6) PACC(36,5,7) PACC(37,5,8) PACC(38,5,9)
  PACC(39,6,7) PACC(40,6,8) PACC(41,6,9)
  PACC(42,7,8) PACC(43,7,9)
  PACC(44,8,9)

  // ---- encoding angles: wave-uniform -> SGPRs ----
  float th[10], ph[10];
  #pragma unroll
  for (int q = 0; q < 10; ++q) {
    th[q] = rfl(c[1270 + q]);
    ph[q] = rfl(dcp[1270 + q]);
  }

  // ---- per-lane R product: lane r computes R_r for qubits 6..9 ----
  float Rr_l, Ri_l;
  {
    const int rr = lane & 15;
    float prr = 1.0f, pri = 0.0f;
    #pragma unroll
    for (int t = 0; t < 4; ++t) {
      float cy, sy; __sincosf(0.5f * th[6 + t], &sy, &cy);
      float cz, sz; __sincosf(0.5f * ph[6 + t], &sz, &cz);
      const bool b = ((rr >> (3 - t)) & 1) != 0;
      const float fr = b ? sy * cz : cy * cz;
      const float fi = b ? sy * sz : -cy * sz;
      const float nr = prr * fr - pri * fi;
      pri = prr * fi + pri * fr;
      prr = nr;
    }
    Rr_l = prr; Ri_l = pri;
  }

  // ---- closed-form initial state: (prod_q RZ(ph)RY(th)|0>) * e^{i h} ----
  v2 st[16];
  {
    v2 L; L.x = 1.0f; L.y = 0.0f;
    #pragma unroll
    for (int q = 0; q < 6; ++q) {
      float cy, sy; __sincosf(0.5f * th[q], &sy, &cy);
      float cz, sz; __sincosf(0.5f * ph[q], &sz, &cz);
      const bool b = ((lane >> (5 - q)) & 1) != 0;
      const float zr = b ? sy * cz : cy * cz;
      const float zi = b ? sy * sz : -cy * sz;
      L = zr * L + zi * sneg(L);
    }
    #pragma unroll
    for (int r = 0; r < 16; ++r) {
      const int b3 = (r >> 3) & 1, b2 = (r >> 2) & 1, b1 = (r >> 1) & 1, b0 = r & 1;
      const float Rr = RLg(r, Rr_l);
      const float Ri = RLg(r, Ri_l);
      float h = Cc;
      h += b3 ? -dcoef[0] : dcoef[0];
      h += b2 ? -dcoef[1] : dcoef[1];
      h += b1 ? -dcoef[2] : dcoef[2];
      h += b0 ? -dcoef[3] : dcoef[3];
      h += (b3 ^ b2) ? -ecoef[0] : ecoef[0];
      h += (b3 ^ b1) ? -ecoef[1] : ecoef[1];
      h += (b3 ^ b0) ? -ecoef[2] : ecoef[2];
      h += (b2 ^ b1) ? -ecoef[3] : ecoef[3];
      h += (b2 ^ b0) ? -ecoef[4] : ecoef[4];
      h += (b1 ^ b0) ? -ecoef[5] : ecoef[5];
      float sn, cs; __sincosf(h, &sn, &cs);
      const v2 p = cs * L + sn * sneg(L);
      st[r] = Rr * p + Ri * sneg(p);
    }
  }

  // ---- layers with per-wave gate rotation (gates within a layer commute) ----
  const int off = __builtin_amdgcn_readfirstlane(
      (int)((blockIdx.x + 3u * (unsigned)wave) % 10u));
  for (int i = 0; i < 10; ++i) {
    int q = i + off; if (q >= 10) q -= 10;
    switch (q) {
      case 0: GATE0(0,0) break;
      case 1: GATE0(1,1) break;
      case 2: GATE0(2,2) break;
      case 3: GATE0(3,3) break;
      case 4: GATE0(4,4) break;
      case 5: GATE0(5,5) break;
      case 6: GATE0(6,6) break;
      case 7: GATE0(7,7) break;
      case 8: GATE0(8,8) break;
      case 9: GATE0(9,9) break;
    }
  }
  for (int i = 0; i < 10; ++i) {
    int q = i + off; if (q >= 10) q -= 10;
    switch (q) {
      case 0: GATE1(10,0) break;
      case 1: GATE1(11,1) break;
      case 2: GATE1(12,2) break;
      case 3: GATE1(13,3) break;
      case 4: GATE1(14,4) break;
      case 5: GATE1(15,5) break;
      case 6: GATE1(16,6) break;
      case 7: GATE1(17,7) break;
      case 8: GATE1(18,8) break;
      case 9: GATE1(19,9) break;
    }
  }
  for (int i = 0; i < 10; ++i) {
    int q = i + off; if (q >= 10) q -= 10;
    switch (q) {
      case 0: GATE2(20,0) break;
      case 1: GATE2(21,1) break;
      case 2: GATE2(22,2) break;
      case 3: GATE2(23,3) break;
      case 4: GATE2(24,4) break;
      case 5: GATE2(25,5) break;
      case 6: GATE2(26,6) break;
      case 7: GATE2(27,7) break;
      case 8: GATE2(28,8) break;
      case 9: GATE2(29,9) break;
    }
  }
  // (CNOT block rng=3 folded into measurement sign masks via Q3)

  // ---- measurement: Z expvals with Q3-row parities, funnel, projection ----
  float e[10] = {0,0,0,0,0,0,0,0,0,0};
  #pragma unroll
  for (int r = 0; r < 16; ++r) {
    const v2 sq = st[r] * st[r];
    const float pp = sq.x + sq.y;
    #pragma unroll
    for (int q = 0; q < 10; ++q) {
      const bool s = (__builtin_popcount(r & (int)(Q3.row[9-q] & 15u)) & 1) != 0;
      e[q] += s ? -pp : pp;
    }
  }
  float mv[10];
  #pragma unroll
  for (int q = 0; q < 10; ++q) {
    const int wl = (int)((Q3.row[9-q] >> 4) & 63u);
    const bool sl = wl ? ((__builtin_popcount(lane & wl) & 1) != 0) : false;
    mv[q] = sl ? -e[q] : e[q];
  }
  {
    float fb[6];
    #pragma unroll
    for (int i = 0; i < 5; ++i) {
      const float send = (lane & 1) ? mv[i] : mv[i + 5];
      const float recv = xshfl<1>(send);
      const float keep = (lane & 1) ? mv[i + 5] : mv[i];
      fb[i] = keep + recv;
    }
    fb[5] = 0.0f;
    fstage<2, 3>(fb, lane);
    fb[3] = 0.0f;
    fstage<4, 2>(fb, lane);
    fstage<8, 1>(fb, lane);
    fb[0] += xshfl<16>(fb[0]);
    fb[0] += xshfl<32>(fb[0]);
    float ev[10];
    #pragma unroll
    for (int k = 0; k < 10; ++k) ev[k] = RLg(holder_lane10(k), fb[0]);
    if (lane < 3) {
      float acc = b_proj[lane];
      #pragma unroll
      for (int i = 0; i < 10; ++i) acc += w_proj[lane * 10 + i] * ev[i];
      out[(size_t)bid * 3 + lane] = acc;
    }
  }
}

extern "C" void kernel_launch(void* const* d_in, const int* in_sizes, int n_in,
                              void* d_out, int out_size, void* d_ws, size_t ws_size,
                              hipStream_t stream) {
  (void)in_sizes; (void)n_in; (void)d_ws; (void)ws_size; (void)out_size;
  const float* c_kt      = (const float*)d_in[0];
  const float* dc_kt     = (const float*)d_in[1];
  const float* vw        = (const float*)d_in[2];
  const float* w_proj    = (const float*)d_in[3];
  const float* b_proj    = (const float*)d_in[4];
  const float* log_alpha = (const float*)d_in[5];
  float* out = (float*)d_out;
  // 4096 batch elems, 1 wave each, 4 waves per 256-thread block
  qhl_kernel<<<dim3(1024), dim3(256), 0, stream>>>(c_kt, dc_kt, vw, w_proj,
                                                   b_proj, log_alpha, out);
}

// Round 10
// 118.139 us; speedup vs baseline: 1.0681x; 1.0681x over previous
//
#include <hip/hip_runtime.h>

// One wave (64 lanes) per batch element. State: 1024 complex amps = 16/lane
// as packed float2. s = lane*16 + r; qubit q <-> s-bit (9-q). No LDS staging.
//
// R12: CNOTs folded into gates by GF(2) conjugation (126us bench / 55.7us disp).
// R16 WIN (117.8us / 47.5us): gate complex MAC as v_pk_mul/v_pk_fma VOP3P.
// R17 NEUTRAL, R18/R19/R20 REGRESS. Pattern: runtime tracks instruction/ds-op
//   count; only op-count reductions win.
// R21: lane-bit assignment optimized by compile-time search. Which gates need
//   the LDS crossbar = whether their conjugated mask touches PHYSICAL lane
//   bits 4-5 (DPP covers any xor in bits 0-3 at <=2 ops). We may permute
//   which s-bit sits at which physical lane bit: search all C(6,2)=15
//   choices of the two slots mapped to bits 4/5, minimizing #masks touching
//   them across all 30 gates. Defaults to identity when no better (= exact
//   R16 behavior). Full DPP table for masks 1..15 (verified in R15 run);
//   LDS path only for ML>=16.

typedef float v2 __attribute__((ext_vector_type(2)));

// ===== compile-time GF(2) linear algebra on 10-bit indices =====
struct M10 { unsigned row[10]; };
constexpr M10 mident() { M10 m{}; for (int i=0;i<10;++i) m.row[i]=1u<<i; return m; }
constexpr M10 mmul(M10 A, M10 B) {   // (A*B)s = A(Bs); row_i(AB) = xor_{j in row_i(A)} row_j(B)
  M10 C{};
  for (int i=0;i<10;++i){ unsigned x=0; for (int j=0;j<10;++j) if ((A.row[i]>>j)&1u) x ^= B.row[j]; C.row[i]=x; }
  return C;
}
constexpr M10 cnotT(int ctrl, int rng) {     // s -> s ^ s_cb*e_tb  (self-inverse)
  const int tgt = (ctrl + rng) % 10;
  const int cb = 9 - ctrl, tb = 9 - tgt;
  M10 m = mident(); m.row[tb] = (1u<<tb)|(1u<<cb); return m;
}
// block applied ctrl=0..9 sequentially: psi_out(s) = psi_in(T0*T1*...*T9 s)
constexpr M10 blockPinv(int rng) { M10 m = cnotT(0,rng); for (int c=1;c<10;++c) m = mmul(m, cnotT(c,rng)); return m; }
constexpr M10 blockP(int rng)    { M10 m = cnotT(9,rng); for (int c=8;c>=0;--c) m = mmul(m, cnotT(c,rng)); return m; }
constexpr unsigned mcol(M10 A, int c) { unsigned x=0; for (int i=0;i<10;++i) x |= ((A.row[i]>>c)&1u)<<i; return x; }
constexpr int par(unsigned x){ int p=0; for (int i=0;i<10;++i) p ^= (int)((x>>i)&1u); return p; }
constexpr int topbit4(int x){ int b=0; for (int i=1;i<4;++i) if (x>>i) b=i; return 1<<b; }

constexpr M10 Q1  = blockP(1);
constexpr M10 Q1i = blockPinv(1);
constexpr M10 Q2  = mmul(blockP(2), Q1);
constexpr M10 Q2i = mmul(Q1i, blockPinv(2));
constexpr M10 Q3  = mmul(blockP(3), Q2);

static_assert(mmul(Q1, Q1i).row[0]==1u && mmul(Q1,Q1i).row[9]==(1u<<9), "inv1");
static_assert(mmul(Q2, Q2i).row[0]==1u && mmul(Q2,Q2i).row[7]==(1u<<7), "inv2");
static_assert(par(mcol(Q1i,0)&Q1.row[0]) && par(mcol(Q1i,5)&Q1.row[5]) && par(mcol(Q1i,9)&Q1.row[9]), "dual1");
static_assert(par(mcol(Q2i,0)&Q2.row[0]) && par(mcol(Q2i,4)&Q2.row[4]) && par(mcol(Q2i,9)&Q2.row[9]), "dual2");

// ===== R21: lane-bit assignment search =====
// Lane slot s (0..5) holds s-bit 4+s. Choose which two slots map to physical
// lane bits 4,5 (the only bits DPP cannot cross) minimizing #gate masks that
// touch them. Remaining slots map to physical 0..3 (any order; all <=2 DPP).
constexpr unsigned gmaskM(int l, int q) {
  return l==0 ? (1u<<(9-q)) : (l==1 ? mcol(Q1i,9-q) : mcol(Q2i,9-q));
}
constexpr int pairCost(int a, int b) {
  int c=0;
  for (int l=0;l<3;++l) for (int q=0;q<10;++q) {
    const unsigned ml = (gmaskM(l,q)>>4)&63u;
    if (ml & ((1u<<a)|(1u<<b))) ++c;
  }
  return c;
}
struct Perm { int np[6]; };
constexpr Perm bestPerm() {
  int bA=4, bB=5, bC=pairCost(4,5);           // identity default (ties keep it)
  for (int a=0;a<6;++a) for (int b=a+1;b<6;++b) {
    const int c = pairCost(a,b);
    if (c < bC) { bC=c; bA=a; bB=b; }
  }
  Perm p{}; int nxt=0;
  for (int s=0;s<6;++s) {
    if (s==bA) p.np[s]=4; else if (s==bB) p.np[s]=5; else p.np[s]=nxt++;
  }
  return p;
}
constexpr Perm PP = bestPerm();
constexpr bool permOK() {
  int seen=0;
  for (int s=0;s<6;++s){ if (PP.np[s]<0||PP.np[s]>5) return false;
    if ((seen>>PP.np[s])&1) return false; seen|=1<<PP.np[s]; }
  return seen==63;
}
static_assert(permOK(), "perm");
constexpr unsigned pmask(unsigned m) {        // permute lane part of 10-bit mask
  unsigned r = m & 15u;
  for (int s=0;s<6;++s) if ((m>>(4+s))&1u) r |= 1u<<(4+PP.np[s]);
  return r;
}
constexpr int popc(unsigned x){ int c=0; for(int i=0;i<10;++i) c+=(int)((x>>i)&1u); return c; }
static_assert(popc(pmask(0x3FFu))==10 && pmask(15u)==15u, "pmask");

// ===== cross-lane xor: full DPP table 1..15, ds_swizzle 16..31, bpermute >=32 =====
template<int CTRL>
__device__ __forceinline__ float dppf(float v) {
  return __int_as_float(__builtin_amdgcn_update_dpp(
      0, __float_as_int(v), CTRL, 0xF, 0xF, true));
}

template<int MASK>
__device__ __forceinline__ float xany(float v, int baddr) {
  if constexpr (MASK == 0) return v;
  else if constexpr (MASK == 1)  return dppf<0xB1>(v);
  else if constexpr (MASK == 2)  return dppf<0x4E>(v);
  else if constexpr (MASK == 3)  return dppf<0x1B>(v);
  else if constexpr (MASK == 4)  return dppf<0x141>(dppf<0x1B>(v));   // 7^3
  else if constexpr (MASK == 5)  return dppf<0x141>(dppf<0x4E>(v));   // 7^2
  else if constexpr (MASK == 6)  return dppf<0x141>(dppf<0xB1>(v));   // 7^1
  else if constexpr (MASK == 7)  return dppf<0x141>(v);               // row_half_mirror
  else if constexpr (MASK == 8)  return dppf<0x128>(v);               // row_ror:8
  else if constexpr (MASK == 9)  return dppf<0x128>(dppf<0xB1>(v));
  else if constexpr (MASK == 10) return dppf<0x128>(dppf<0x4E>(v));
  else if constexpr (MASK == 11) return dppf<0x128>(dppf<0x1B>(v));
  else if constexpr (MASK == 12) return dppf<0x140>(dppf<0x1B>(v));   // 15^3
  else if constexpr (MASK == 13) return dppf<0x140>(dppf<0x4E>(v));   // 15^2
  else if constexpr (MASK == 14) return dppf<0x140>(dppf<0xB1>(v));   // 15^1
  else if constexpr (MASK == 15) return dppf<0x140>(v);               // row_mirror
  else if constexpr (MASK < 32) return __int_as_float(__builtin_amdgcn_ds_swizzle(__float_as_int(v), (MASK<<10)|0x1F));
  else return __int_as_float(__builtin_amdgcn_ds_bpermute(baddr, __float_as_int(v)));
}
template<int MASK>
__device__ __forceinline__ v2 xany2(v2 v, int baddr) {
  v2 r; r.x = xany<MASK>(v.x, baddr); r.y = xany<MASK>(v.y, baddr); return r;
}

// pow2-only xor (reductions; physical lane space, unaffected by perm)
template<int LM>
__device__ __forceinline__ float xshfl(float v) {
  if constexpr (LM == 1) return dppf<0xB1>(v);
  else if constexpr (LM == 2) return dppf<0x4E>(v);
  else if constexpr (LM == 4) return dppf<0x141>(dppf<0x1B>(v));
  else if constexpr (LM == 8) return dppf<0x128>(v);
  else if constexpr (LM == 16) return __int_as_float(__builtin_amdgcn_ds_swizzle(__float_as_int(v), 0x401F));
  else return __shfl_xor(v, 32);
}

// multi-value funnel stage: NP pairs (i, i+NP) across lane bit B
template<int B, int NP>
__device__ __forceinline__ void fstage(float* p, int lane) {
  #pragma unroll
  for (int i = 0; i < NP; ++i) {
    const float send = (lane & B) ? p[i] : p[i + NP];
    const float recv = xshfl<B>(send);
    const float keep = (lane & B) ? p[i + NP] : p[i];
    p[i] = keep + recv;
  }
}
constexpr int holder_lane45(int v) {
  const int a = v >= 24; int r = v - 24 * a;
  const int b = r >= 12; r -= 12 * b;
  const int c = r >= 6;  r -= 6 * c;
  const int d = r >= 3;  r -= 3 * d;
  const int e = r >= 2;  r -= 2 * e;
  return a | (b << 1) | (c << 2) | (d << 3) | (e << 4) | (r << 5);
}
constexpr int holder_lane10(int v) {
  const int a = v >= 5; int r = v - 5 * a;
  const int b = r >= 3; r -= 3 * b;
  const int c = r >= 2; r -= 2 * c;
  return a | (b << 1) | (c << 2) | (r << 3);
}

__device__ __forceinline__ float rfl(float x) {
  return __int_as_float(__builtin_amdgcn_readfirstlane(__float_as_int(x)));
}
#define RLg(g_, x_) __int_as_float(__builtin_amdgcn_readlane(__float_as_int(x_), (g_)))

__device__ __forceinline__ float fast_tanh(float x) {
  return 1.0f - 2.0f / (__expf(2.0f * x) + 1.0f);
}
__device__ __forceinline__ v2 sneg(v2 a) {       // i*a: (re,im)->(-im,re)
  v2 r; r.x = -a.y; r.y = a.x; return r;
}

// ===== packed complex MAC core: 4 VOP3P ops per amplitude (R16, verified) =====
__device__ __forceinline__ v2 gate_upd_p(v2 a, v2 p, v2 ar2, v2 ai2, v2 br2, v2 bi2) {
  v2 acc;
  asm("v_pk_mul_f32 %0, %1, %2" : "=v"(acc) : "v"(ar2), "v"(a));
  asm("v_pk_fma_f32 %0, %1, %2, %0 op_sel:[1,0,0] op_sel_hi:[0,1,1] neg_lo:[1,0,0]"
      : "+v"(acc) : "v"(a), "v"(ai2));
  asm("v_pk_fma_f32 %0, %1, %2, %0"
      : "+v"(acc) : "v"(p), "v"(br2));
  asm("v_pk_fma_f32 %0, %1, %2, %0 op_sel:[1,0,0] op_sel_hi:[0,1,1] neg_lo:[1,0,0]"
      : "+v"(acc) : "v"(p), "v"(bi2));
  return acc;
}
__device__ __forceinline__ v2 gate_upd_m(v2 a, v2 p, v2 ar2, v2 ai2, v2 br2, v2 bi2) {
  v2 acc;
  asm("v_pk_mul_f32 %0, %1, %2" : "=v"(acc) : "v"(ar2), "v"(a));
  asm("v_pk_fma_f32 %0, %1, %2, %0 op_sel:[1,0,0] op_sel_hi:[0,1,1] neg_hi:[1,0,0]"
      : "+v"(acc) : "v"(a), "v"(ai2));
  asm("v_pk_fma_f32 %0, %1, %2, %0 neg_lo:[1,0,0] neg_hi:[1,0,0]"
      : "+v"(acc) : "v"(p), "v"(br2));
  asm("v_pk_fma_f32 %0, %1, %2, %0 op_sel:[1,0,0] op_sel_hi:[0,1,1] neg_lo:[1,0,0]"
      : "+v"(acc) : "v"(p), "v"(bi2));
  return acc;
}

// ===== general conjugated gate (R17 structure; LDS path only for ML>=16) =====
template<int M, int V>
__device__ __forceinline__ void gate_g(v2 (&st)[16], int lane,
                                       float ar, float ai, float br, float bi) {
  constexpr int MR = M & 15, ML = (M >> 4) & 63;
  constexpr int VR = V & 15, VL = (V >> 4) & 63;
  bool hl = false;
  if constexpr (VL != 0) hl = (__builtin_popcount(lane & VL) & 1) != 0;
  const float aiX = hl ? -ai : ai;
  const float brX = hl ? -br : br;
  v2 ar2; ar2.x = ar;  ar2.y = ar;
  v2 ai2; ai2.x = aiX; ai2.y = aiX;
  v2 br2; br2.x = brX; br2.y = brX;
  v2 bi2; bi2.x = bi;  bi2.y = bi;
  int baddr = 0;
  if constexpr (ML >= 32) baddr = (lane ^ ML) << 2;
  if constexpr (ML >= 16) {
    // LDS-path gate: batch all shuffles (partner of st[r] is shuffle of st[r^MR])
    v2 pf[16];
    #pragma unroll
    for (int r = 0; r < 16; ++r) pf[r] = xany2<ML>(st[r ^ MR], baddr);
    #pragma unroll
    for (int r = 0; r < 16; ++r) {
      if ((__builtin_popcount(r & VR) & 1) == 0)
        st[r] = gate_upd_p(st[r], pf[r], ar2, ai2, br2, bi2);
      else
        st[r] = gate_upd_m(st[r], pf[r], ar2, ai2, br2, bi2);
    }
  } else if constexpr (MR == 0) {
    #pragma unroll
    for (int r = 0; r < 16; ++r) {
      const v2 p = xany2<ML>(st[r], baddr);
      const v2 a = st[r];
      if ((__builtin_popcount(r & VR) & 1) == 0)
        st[r] = gate_upd_p(a, p, ar2, ai2, br2, bi2);
      else
        st[r] = gate_upd_m(a, p, ar2, ai2, br2, bi2);
    }
  } else {
    constexpr int HB = topbit4(MR);
    #pragma unroll
    for (int r = 0; r < 16; ++r) {
      if ((r & HB) == 0) {
        const int r1 = r ^ MR;
        v2 pa, pb;
        if constexpr (ML == 0) { pa = st[r1]; pb = st[r]; }
        else { pa = xany2<ML>(st[r1], baddr); pb = xany2<ML>(st[r], baddr); }
        const v2 a = st[r], b = st[r1];
        if ((__builtin_popcount(r & VR) & 1) == 0)
          st[r] = gate_upd_p(a, pa, ar2, ai2, br2, bi2);
        else
          st[r] = gate_upd_m(a, pa, ar2, ai2, br2, bi2);
        if ((__builtin_popcount(r1 & VR) & 1) == 0)
          st[r1] = gate_upd_p(b, pb, ar2, ai2, br2, bi2);
        else
          st[r1] = gate_upd_m(b, pb, ar2, ai2, br2, bi2);
      }
    }
  }
}

// half_ang decomposition: C(lane) + d[j]*z_j(r) + e[ij]*z_i(r)z_j(r)
// Lane-bit selects use the permuted physical positions PP.np[5-I].
template<int I, int J>
__device__ __forceinline__ void pair_accum(float t, int lane, float& Cc,
                                           float (&dcf)[4], float (&ecf)[6]) {
  if constexpr (J <= 5) {
    const bool diff = (((lane >> PP.np[5 - I]) ^ (lane >> PP.np[5 - J])) & 1) != 0;
    Cc += diff ? -t : t;
  } else if constexpr (I <= 5) {
    const bool b = ((lane >> PP.np[5 - I]) & 1) != 0;
    dcf[J - 6] += b ? -t : t;
  } else {
    constexpr int eb = (I == 6) ? 0 : (I == 7) ? 3 : 5;
    ecf[eb + (J - I - 1)] = t;
  }
}
#define PACC(v_, i_, j_) pair_accum<i_, j_>(RLg(holder_lane45(v_), tl), lane, Cc, dcoef, ecoef);

#define GATE0(g_, q_) gate_g<(int)pmask(1u<<(9-(q_))), (int)pmask(1u<<(9-(q_)))>(st, lane, \
    RLg(g_,Mr00), RLg(g_,Mi00), RLg(g_,Mr01), RLg(g_,Mi01));
#define GATE1(g_, q_) gate_g<(int)pmask(mcol(Q1i,9-(q_))), (int)pmask(Q1.row[9-(q_)])>(st, lane, \
    RLg(g_,Mr00), RLg(g_,Mi00), RLg(g_,Mr01), RLg(g_,Mi01));
#define GATE2(g_, q_) gate_g<(int)pmask(mcol(Q2i,9-(q_))), (int)pmask(Q2.row[9-(q_)])>(st, lane, \
    RLg(g_,Mr00), RLg(g_,Mi00), RLg(g_,Mr01), RLg(g_,Mi01));

extern "C" __global__ void __launch_bounds__(256, 2)
qhl_kernel(const float* __restrict__ c_kt, const float* __restrict__ dc_kt,
           const float* __restrict__ vw,  const float* __restrict__ w_proj,
           const float* __restrict__ b_proj, const float* __restrict__ log_alpha,
           float* __restrict__ out) {
  const int wave = threadIdx.x >> 6;
  const int lane = threadIdx.x & 63;
  const int bid  = blockIdx.x * 4 + wave;

  const float* c   = c_kt  + (size_t)bid * 1280;
  const float* dcp = dc_kt + (size_t)bid * 1280;

  // ---- per-lane gate-matrix precompute: lane g -> gate (l=g/10, q=g%10)
  float Mr00, Mi00, Mr01, Mi01;
  {
    const int g = lane < 30 ? lane : 0;
    const int l = g / 10, q = g - l * 10;
    const float w0 = vw[g*3+0], w1 = vw[g*3+1], w2 = vw[g*3+2];
    float cY, sY; __sincosf(0.5f*w1, &sY, &cY);
    float ca, sa; __sincosf(0.5f*(w0+w2), &sa, &ca);
    float cb, sb; __sincosf(0.5f*(w0-w2), &sb, &cb);
    const float r00r =  cY*ca, r00i = -cY*sa, r01r = -sY*cb, r01i = -sY*sb;
    if (l == 0) {
      Mr00 = r00r; Mi00 = r00i; Mr01 = r01r; Mi01 = r01i;
    } else {
      const float thq = c[1270 + q], phq = dcp[1270 + q];
      float cy, sy; __sincosf(0.25f * thq, &sy, &cy);
      float cz, sz; __sincosf(0.25f * phq, &sz, &cz);
      const float e00r =  cy*cz, e00i = -cy*sz, e01r = -sy*cz, e01i =  sy*sz;
      const float e10r =  sy*cz, e10i =  sy*sz, e11r =  cy*cz, e11i =  cy*sz;
      Mr00 = r00r*e00r - r00i*e00i + r01r*e10r - r01i*e10i;
      Mi00 = r00r*e00i + r00i*e00r + r01r*e10i + r01i*e10r;
      Mr01 = r00r*e01r - r00i*e01i + r01r*e11r - r01i*e11i;
      Mi01 = r00r*e01i + r00i*e01r + r01r*e11i + r01i*e11r;
    }
  }

  // ---- correlation rows packed as (t=lane, t=lane+64) float2 pairs ----
  v2 ym[10];
  {
    const float2* c0 = (const float2*)(c   + lane * 10);
    const float2* d0 = (const float2*)(dcp + lane * 10);
    const float2* c1 = (const float2*)(c   + (lane + 64) * 10);
    const float2* d1 = (const float2*)(dcp + (lane + 64) * 10);
    #pragma unroll
    for (int k = 0; k < 5; ++k) {
      const float2 a0 = c0[k], b0 = d0[k], a1 = c1[k], b1 = d1[k];
      ym[2*k].x   = a0.x + 0.5f * b0.x;  ym[2*k].y   = a1.x + 0.5f * b1.x;
      ym[2*k+1].x = a0.y + 0.5f * b0.y;  ym[2*k+1].y = a1.y + 0.5f * b1.y;
    }
  }

  // ---- row stats via 10-value funnels ----
  {
    float mb[6];
    float m10a[10];
    #pragma unroll
    for (int k = 0; k < 10; ++k) m10a[k] = ym[k].x + ym[k].y;
    #pragma unroll
    for (int i = 0; i < 5; ++i) {
      const float send = (lane & 1) ? m10a[i] : m10a[i + 5];
      const float recv = xshfl<1>(send);
      const float keep = (lane & 1) ? m10a[i + 5] : m10a[i];
      mb[i] = keep + recv;
    }
    mb[5] = 0.0f;
    fstage<2, 3>(mb, lane);
    mb[3] = 0.0f;
    fstage<4, 2>(mb, lane);
    fstage<8, 1>(mb, lane);
    mb[0] += xshfl<16>(mb[0]);
    mb[0] += xshfl<32>(mb[0]);
    mb[0] *= (1.0f / 128.0f);
    #pragma unroll
    for (int k = 0; k < 10; ++k) {
      const float mk = RLg(holder_lane10(k), mb[0]);
      ym[k].x -= mk; ym[k].y -= mk;
    }
    float s10[10];
    #pragma unroll
    for (int k = 0; k < 10; ++k) { const v2 sq = ym[k] * ym[k]; s10[k] = sq.x + sq.y; }
    #pragma unroll
    for (int i = 0; i < 5; ++i) {
      const float send = (lane & 1) ? s10[i] : s10[i + 5];
      const float recv = xshfl<1>(send);
      const float keep = (lane & 1) ? s10[i + 5] : s10[i];
      mb[i] = keep + recv;
    }
    mb[5] = 0.0f;
    fstage<2, 3>(mb, lane);
    mb[3] = 0.0f;
    fstage<4, 2>(mb, lane);
    fstage<8, 1>(mb, lane);
    mb[0] += xshfl<16>(mb[0]);
    mb[0] += xshfl<32>(mb[0]);
    const float rsv = fminf(__builtin_amdgcn_rsqf(mb[0] * (1.0f / 127.0f)), 1e8f);
    #pragma unroll
    for (int k = 0; k < 10; ++k) {
      const float rk = RLg(holder_lane10(k), rsv);
      ym[k].x *= rk; ym[k].y *= rk;
    }
  }

  // ---- 45 pair dots via one 48-slot funnel; tanh lane-parallel ----
  const float expA = rfl(__expf(log_alpha[0]));
  float Cc = 0.0f, dcoef[4] = {0, 0, 0, 0}, ecoef[6];
  float tl;
  {
    constexpr int PI_[45] = {0,0,0,0,0,0,0,0,0, 1,1,1,1,1,1,1,1, 2,2,2,2,2,2,2,
                             3,3,3,3,3,3, 4,4,4,4,4, 5,5,5,5, 6,6,6, 7,7, 8};
    constexpr int PJ_[45] = {1,2,3,4,5,6,7,8,9, 2,3,4,5,6,7,8,9, 3,4,5,6,7,8,9,
                             4,5,6,7,8,9, 5,6,7,8,9, 6,7,8,9, 7,8,9, 8,9, 9};
    float p[48];
    #pragma unroll
    for (int v = 0; v < 45; ++v) {
      const v2 pr = ym[PI_[v]] * ym[PJ_[v]];
      p[v] = pr.x + pr.y;
    }
    p[45] = 0.0f; p[46] = 0.0f; p[47] = 0.0f;
    fstage<1, 24>(p, lane);
    fstage<2, 12>(p, lane);
    fstage<4, 6>(p, lane);
    fstage<8, 3>(p, lane);
    p[3] = 0.0f;
    fstage<16, 2>(p, lane);
    fstage<32, 1>(p, lane);
    const float sc = expA * (1.0f / 127.0f);
    tl = -1.5707963267948966f * fast_tanh(p[0] * sc);
  }
  PACC(0,0,1) PACC(1,0,2) PACC(2,0,3) PACC(3,0,4) PACC(4,0,5) PACC(5,0,6) PACC(6,0,7) PACC(7,0,8) PACC(8,0,9)
  PACC(9,1,2) PACC(10,1,3) PACC(11,1,4) PACC(12,1,5) PACC(13,1,6) PACC(14,1,7) PACC(15,1,8) PACC(16,1,9)
  PACC(17,2,3) PACC(18,2,4) PACC(19,2,5) PACC(20,2,6) PACC(21,2,7) PACC(22,2,8) PACC(23,2,9)
  PACC(24,3,4) PACC(25,3,5) PACC(26,3,6) PACC(27,3,7) PACC(28,3,8) PACC(29,3,9)
  PACC(30,4,5) PACC(31,4,6) PACC(32,4,7) PACC(33,4,8) PACC(34,4,9)
  PACC(35,5,6) PACC(36,5,7) PACC(37,5,8) PACC(38,5,9)
  PACC(39,6,7) PACC(40,6,8) PACC(41,6,9)
  PACC(42,7,8) PACC(43,7,9)
  PACC(44,8,9)

  // ---- encoding angles: wave-uniform -> SGPRs ----
  float th[10], ph[10];
  #pragma unroll
  for (int q = 0; q < 10; ++q) {
    th[q] = rfl(c[1270 + q]);
    ph[q] = rfl(dcp[1270 + q]);
  }

  // ---- per-lane R product: lane r computes R_r for qubits 6..9 ----
  float Rr_l, Ri_l;
  {
    const int rr = lane & 15;
    float prr = 1.0f, pri = 0.0f;
    #pragma unroll
    for (int t = 0; t < 4; ++t) {
      float cy, sy; __sincosf(0.5f * th[6 + t], &sy, &cy);
      float cz, sz; __sincosf(0.5f * ph[6 + t], &sz, &cz);
      const bool b = ((rr >> (3 - t)) & 1) != 0;
      const float fr = b ? sy * cz : cy * cz;
      const float fi = b ? sy * sz : -cy * sz;
      const float nr = prr * fr - pri * fi;
      pri = prr * fi + pri * fr;
      prr = nr;
    }
    Rr_l = prr; Ri_l = pri;
  }

  // ---- closed-form initial state: (prod_q RZ(ph)RY(th)|0>) * e^{i h} ----
  // qubit q (0..5): s-bit 9-q lives at lane slot 5-q -> physical PP.np[5-q]
  v2 st[16];
  {
    v2 L; L.x = 1.0f; L.y = 0.0f;
    #pragma unroll
    for (int q = 0; q < 6; ++q) {
      float cy, sy; __sincosf(0.5f * th[q], &sy, &cy);
      float cz, sz; __sincosf(0.5f * ph[q], &sz, &cz);
      const bool b = ((lane >> PP.np[5 - q]) & 1) != 0;
      const float zr = b ? sy * cz : cy * cz;
      const float zi = b ? sy * sz : -cy * sz;
      L = zr * L + zi * sneg(L);
    }
    #pragma unroll
    for (int r = 0; r < 16; ++r) {
      const int b3 = (r >> 3) & 1, b2 = (r >> 2) & 1, b1 = (r >> 1) & 1, b0 = r & 1;
      const float Rr = RLg(r, Rr_l);
      const float Ri = RLg(r, Ri_l);
      float h = Cc;
      h += b3 ? -dcoef[0] : dcoef[0];
      h += b2 ? -dcoef[1] : dcoef[1];
      h += b1 ? -dcoef[2] : dcoef[2];
      h += b0 ? -dcoef[3] : dcoef[3];
      h += (b3 ^ b2) ? -ecoef[0] : ecoef[0];
      h += (b3 ^ b1) ? -ecoef[1] : ecoef[1];
      h += (b3 ^ b0) ? -ecoef[2] : ecoef[2];
      h += (b2 ^ b1) ? -ecoef[3] : ecoef[3];
      h += (b2 ^ b0) ? -ecoef[4] : ecoef[4];
      h += (b1 ^ b0) ? -ecoef[5] : ecoef[5];
      float sn, cs; __sincosf(h, &sn, &cs);
      const v2 p = cs * L + sn * sneg(L);
      st[r] = Rr * p + Ri * sneg(p);
    }
  }

  // ---- layer 0 (standard frame) ----
  GATE0(0,0) GATE0(1,1) GATE0(2,2) GATE0(3,3) GATE0(4,4)
  GATE0(5,5) GATE0(6,6) GATE0(7,7) GATE0(8,8) GATE0(9,9)
  // ---- layer 1 conjugated by Q1 (CNOT block rng=1 folded) ----
  GATE1(10,0) GATE1(11,1) GATE1(12,2) GATE1(13,3) GATE1(14,4)
  GATE1(15,5) GATE1(16,6) GATE1(17,7) GATE1(18,8) GATE1(19,9)
  // ---- layer 2 conjugated by Q2 (blocks rng=1,2 folded) ----
  GATE2(20,0) GATE2(21,1) GATE2(22,2) GATE2(23,3) GATE2(24,4)
  GATE2(25,5) GATE2(26,6) GATE2(27,7) GATE2(28,8) GATE2(29,9)
  // (CNOT block rng=3 folded into measurement sign masks via Q3)

  // ---- measurement: Z expvals with Q3-row parities (permuted), funnel, projection ----
  float e[10] = {0,0,0,0,0,0,0,0,0,0};
  #pragma unroll
  for (int r = 0; r < 16; ++r) {
    const v2 sq = st[r] * st[r];
    const float pp = sq.x + sq.y;
    #pragma unroll
    for (int q = 0; q < 10; ++q) {
      const bool s = (__builtin_popcount(r & (int)(pmask(Q3.row[9-q]) & 15u)) & 1) != 0;
      e[q] += s ? -pp : pp;
    }
  }
  float mv[10];
  #pragma unroll
  for (int q = 0; q < 10; ++q) {
    const int wl = (int)((pmask(Q3.row[9-q]) >> 4) & 63u);
    const bool sl = wl ? ((__builtin_popcount(lane & wl) & 1) != 0) : false;
    mv[q] = sl ? -e[q] : e[q];
  }
  {
    float fb[6];
    #pragma unroll
    for (int i = 0; i < 5; ++i) {
      const float send = (lane & 1) ? mv[i] : mv[i + 5];
      const float recv = xshfl<1>(send);
      const float keep = (lane & 1) ? mv[i + 5] : mv[i];
      fb[i] = keep + recv;
    }
    fb[5] = 0.0f;
    fstage<2, 3>(fb, lane);
    fb[3] = 0.0f;
    fstage<4, 2>(fb, lane);
    fstage<8, 1>(fb, lane);
    fb[0] += xshfl<16>(fb[0]);
    fb[0] += xshfl<32>(fb[0]);
    float ev[10];
    #pragma unroll
    for (int k = 0; k < 10; ++k) ev[k] = RLg(holder_lane10(k), fb[0]);
    if (lane < 3) {
      float acc = b_proj[lane];
      #pragma unroll
      for (int i = 0; i < 10; ++i) acc += w_proj[lane * 10 + i] * ev[i];
      out[(size_t)bid * 3 + lane] = acc;
    }
  }
}

extern "C" void kernel_launch(void* const* d_in, const int* in_sizes, int n_in,
                              void* d_out, int out_size, void* d_ws, size_t ws_size,
                              hipStream_t stream) {
  (void)in_sizes; (void)n_in; (void)d_ws; (void)ws_size; (void)out_size;
  const float* c_kt      = (const float*)d_in[0];
  const float* dc_kt     = (const float*)d_in[1];
  const float* vw        = (const float*)d_in[2];
  const float* w_proj    = (const float*)d_in[3];
  const float* b_proj    = (const float*)d_in[4];
  const float* log_alpha = (const float*)d_in[5];
  float* out = (float*)d_out;
  // 4096 batch elems, 1 wave each, 4 waves per 256-thread block
  qhl_kernel<<<dim3(1024), dim3(256), 0, stream>>>(c_kt, dc_kt, vw, w_proj,
                                                   b_proj, log_alpha, out);
}

// Round 11
// 117.291 us; speedup vs baseline: 1.0758x; 1.0072x over previous
//
#include <hip/hip_runtime.h>

// One wave (64 lanes) per batch element. State: 1024 complex amps = 16/lane
// as packed float2. Amp index s: s-bit b sits at PHYSICAL position
// AA.phys[b] (0-3 = register-index bits, 4-9 = lane bits 0-5).
//
// R12: CNOTs folded into gates by GF(2) conjugation (126us bench / 55.7us disp).
// R16 WIN (117.8us / 47.5us): gate complex MAC as v_pk_mul/v_pk_fma VOP3P.
// R17-R20: scheduling-shaped changes all neutral/regress. Only op-count
//   reductions win. R21: lane-slot-only search -> identity (neutral).
// R22: FULL layout search. Freedom never exploited: WHICH 4 s-bits are
//   register bits. r-only masks need ZERO shuffles; lane bits 0-3 = DPP;
//   only the 2 hard lane bits (phys 8/9) need ds ops. constexpr search over
//   C(10,4)*C(6,2)=3150 assignments minimizing Sum(gate shuffle cost)
//   (ds=3, dpp=2, r=0), ties keep identity. Any assignment is correct;
//   worst case = exact R16 behavior.

typedef float v2 __attribute__((ext_vector_type(2)));

// ===== compile-time GF(2) linear algebra on 10-bit indices =====
struct M10 { unsigned row[10]; };
constexpr M10 mident() { M10 m{}; for (int i=0;i<10;++i) m.row[i]=1u<<i; return m; }
constexpr M10 mmul(M10 A, M10 B) {   // (A*B)s = A(Bs); row_i(AB) = xor_{j in row_i(A)} row_j(B)
  M10 C{};
  for (int i=0;i<10;++i){ unsigned x=0; for (int j=0;j<10;++j) if ((A.row[i]>>j)&1u) x ^= B.row[j]; C.row[i]=x; }
  return C;
}
constexpr M10 cnotT(int ctrl, int rng) {     // s -> s ^ s_cb*e_tb  (self-inverse)
  const int tgt = (ctrl + rng) % 10;
  const int cb = 9 - ctrl, tb = 9 - tgt;
  M10 m = mident(); m.row[tb] = (1u<<tb)|(1u<<cb); return m;
}
// block applied ctrl=0..9 sequentially: psi_out(s) = psi_in(T0*T1*...*T9 s)
constexpr M10 blockPinv(int rng) { M10 m = cnotT(0,rng); for (int c=1;c<10;++c) m = mmul(m, cnotT(c,rng)); return m; }
constexpr M10 blockP(int rng)    { M10 m = cnotT(9,rng); for (int c=8;c>=0;--c) m = mmul(m, cnotT(c,rng)); return m; }
constexpr unsigned mcol(M10 A, int c) { unsigned x=0; for (int i=0;i<10;++i) x |= ((A.row[i]>>c)&1u)<<i; return x; }
constexpr int par(unsigned x){ int p=0; for (int i=0;i<10;++i) p ^= (int)((x>>i)&1u); return p; }
constexpr int topbit4(int x){ int b=0; for (int i=1;i<4;++i) if (x>>i) b=i; return 1<<b; }

constexpr M10 Q1  = blockP(1);
constexpr M10 Q1i = blockPinv(1);
constexpr M10 Q2  = mmul(blockP(2), Q1);
constexpr M10 Q2i = mmul(Q1i, blockPinv(2));
constexpr M10 Q3  = mmul(blockP(3), Q2);

static_assert(mmul(Q1, Q1i).row[0]==1u && mmul(Q1,Q1i).row[9]==(1u<<9), "inv1");
static_assert(mmul(Q2, Q2i).row[0]==1u && mmul(Q2,Q2i).row[7]==(1u<<7), "inv2");
static_assert(par(mcol(Q1i,0)&Q1.row[0]) && par(mcol(Q1i,5)&Q1.row[5]) && par(mcol(Q1i,9)&Q1.row[9]), "dual1");
static_assert(par(mcol(Q2i,0)&Q2.row[0]) && par(mcol(Q2i,4)&Q2.row[4]) && par(mcol(Q2i,9)&Q2.row[9]), "dual2");

// ===== R22: full layout search =====
struct Masks30 { unsigned m[30]; };
constexpr Masks30 buildMasks() {
  Masks30 g{};
  for (int q=0;q<10;++q) {
    g.m[q]      = 1u<<(9-q);
    g.m[10+q]   = mcol(Q1i,9-q);
    g.m[20+q]   = mcol(Q2i,9-q);
  }
  return g;
}
constexpr Masks30 GM = buildMasks();
constexpr int popcnt10(unsigned x){ int c=0; for(int i=0;i<10;++i) c+=(int)((x>>i)&1u); return c; }

struct Assign { int phys[10]; };   // phys[b]: physical position of s-bit b
constexpr int assignCost(unsigned rsel, unsigned hsel) {
  int c = 0;
  const unsigned easy = 0x3FFu & ~rsel & ~hsel;
  for (int i=0;i<30;++i) {
    const unsigned m = GM.m[i];
    c += (m & hsel) ? 3 : ((m & easy) ? 2 : 0);
  }
  return c;
}
constexpr Assign buildAssign(unsigned rsel, unsigned hsel) {
  Assign a{};
  int rn=0, ln=4, hn=8;
  for (int b=0;b<10;++b) {
    if ((rsel>>b)&1u) a.phys[b]=rn++;
    else if ((hsel>>b)&1u) a.phys[b]=hn++;
    else a.phys[b]=ln++;
  }
  return a;
}
constexpr Assign bestAssign() {
  unsigned bR=0xFu, bH=0x300u;           // identity layout (r=bits0-3, hard=bits8-9)
  int bC = assignCost(bR,bH);
  for (unsigned rsel=0; rsel<1024; ++rsel) {
    if (popcnt10(rsel)!=4) continue;
    const unsigned rest = 0x3FFu & ~rsel;
    for (int h1=0; h1<10; ++h1) {
      if (!((rest>>(unsigned)h1)&1u)) continue;
      for (int h2=h1+1; h2<10; ++h2) {
        if (!((rest>>(unsigned)h2)&1u)) continue;
        const unsigned hsel = (1u<<h1)|(1u<<h2);
        const int cst = assignCost(rsel, hsel);
        if (cst < bC) { bC=cst; bR=rsel; bH=hsel; }
      }
    }
  }
  return buildAssign(bR,bH);
}
constexpr Assign AA = bestAssign();
constexpr bool assignOK(){
  int seen=0;
  for (int b=0;b<10;++b){ const int p=AA.phys[b]; if(p<0||p>9) return false;
    if((seen>>p)&1) return false; seen|=1<<p; }
  int rn=0; for(int q=0;q<10;++q) if (AA.phys[9-q]<4) ++rn;
  return seen==1023 && rn==4;
}
static_assert(assignOK(), "assign");

constexpr unsigned pmask10(unsigned m) {     // s-space mask -> phys-space mask
  unsigned r=0;
  for (int b=0;b<10;++b) if ((m>>b)&1u) r |= 1u<<AA.phys[b];
  return r;
}
static_assert(popcnt10(pmask10(0x3FFu))==10, "pmask10");

// per-qubit tables: qubit q <-> s-bit 9-q
struct QTab { bool isl[10]; int lb[10]; };
constexpr QTab buildQT(){
  QTab t{};
  for(int q=0;q<10;++q){ const int p=AA.phys[9-q]; t.isl[q]=(p>=4); t.lb[q]=(p>=4)?(p-4):0; }
  return t;
}
constexpr QTab QT = buildQT();
struct RQl { int q[4]; int b[4]; };          // the 4 register qubits + their r bits
constexpr RQl buildRQ(){
  RQl r{}; int n=0;
  for(int q=0;q<10;++q){ const int p=AA.phys[9-q]; if (p<4){ r.q[n]=q; r.b[n]=p; ++n; } }
  return r;
}
constexpr RQl RQ = buildRQ();
constexpr int EIDX(int a, int b){            // a>b, r-bit pair -> ecoef slot
  return (a==3&&b==2)?0:(a==3&&b==1)?1:(a==3&&b==0)?2:(a==2&&b==1)?3:(a==2&&b==0)?4:5;
}

// ===== cross-lane xor: full DPP table 1..15, ds_swizzle 16..31, bpermute >=32 =====
template<int CTRL>
__device__ __forceinline__ float dppf(float v) {
  return __int_as_float(__builtin_amdgcn_update_dpp(
      0, __float_as_int(v), CTRL, 0xF, 0xF, true));
}

template<int MASK>
__device__ __forceinline__ float xany(float v, int baddr) {
  if constexpr (MASK == 0) return v;
  else if constexpr (MASK == 1)  return dppf<0xB1>(v);
  else if constexpr (MASK == 2)  return dppf<0x4E>(v);
  else if constexpr (MASK == 3)  return dppf<0x1B>(v);
  else if constexpr (MASK == 4)  return dppf<0x141>(dppf<0x1B>(v));   // 7^3
  else if constexpr (MASK == 5)  return dppf<0x141>(dppf<0x4E>(v));   // 7^2
  else if constexpr (MASK == 6)  return dppf<0x141>(dppf<0xB1>(v));   // 7^1
  else if constexpr (MASK == 7)  return dppf<0x141>(v);               // row_half_mirror
  else if constexpr (MASK == 8)  return dppf<0x128>(v);               // row_ror:8
  else if constexpr (MASK == 9)  return dppf<0x128>(dppf<0xB1>(v));
  else if constexpr (MASK == 10) return dppf<0x128>(dppf<0x4E>(v));
  else if constexpr (MASK == 11) return dppf<0x128>(dppf<0x1B>(v));
  else if constexpr (MASK == 12) return dppf<0x140>(dppf<0x1B>(v));   // 15^3
  else if constexpr (MASK == 13) return dppf<0x140>(dppf<0x4E>(v));   // 15^2
  else if constexpr (MASK == 14) return dppf<0x140>(dppf<0xB1>(v));   // 15^1
  else if constexpr (MASK == 15) return dppf<0x140>(v);               // row_mirror
  else if constexpr (MASK < 32) return __int_as_float(__builtin_amdgcn_ds_swizzle(__float_as_int(v), (MASK<<10)|0x1F));
  else return __int_as_float(__builtin_amdgcn_ds_bpermute(baddr, __float_as_int(v)));
}
template<int MASK>
__device__ __forceinline__ v2 xany2(v2 v, int baddr) {
  v2 r; r.x = xany<MASK>(v.x, baddr); r.y = xany<MASK>(v.y, baddr); return r;
}

// pow2-only xor (reductions; physical lane space)
template<int LM>
__device__ __forceinline__ float xshfl(float v) {
  if constexpr (LM == 1) return dppf<0xB1>(v);
  else if constexpr (LM == 2) return dppf<0x4E>(v);
  else if constexpr (LM == 4) return dppf<0x141>(dppf<0x1B>(v));
  else if constexpr (LM == 8) return dppf<0x128>(v);
  else if constexpr (LM == 16) return __int_as_float(__builtin_amdgcn_ds_swizzle(__float_as_int(v), 0x401F));
  else return __shfl_xor(v, 32);
}

// multi-value funnel stage: NP pairs (i, i+NP) across lane bit B
template<int B, int NP>
__device__ __forceinline__ void fstage(float* p, int lane) {
  #pragma unroll
  for (int i = 0; i < NP; ++i) {
    const float send = (lane & B) ? p[i] : p[i + NP];
    const float recv = xshfl<B>(send);
    const float keep = (lane & B) ? p[i + NP] : p[i];
    p[i] = keep + recv;
  }
}
constexpr int holder_lane45(int v) {
  const int a = v >= 24; int r = v - 24 * a;
  const int b = r >= 12; r -= 12 * b;
  const int c = r >= 6;  r -= 6 * c;
  const int d = r >= 3;  r -= 3 * d;
  const int e = r >= 2;  r -= 2 * e;
  return a | (b << 1) | (c << 2) | (d << 3) | (e << 4) | (r << 5);
}
constexpr int holder_lane10(int v) {
  const int a = v >= 5; int r = v - 5 * a;
  const int b = r >= 3; r -= 3 * b;
  const int c = r >= 2; r -= 2 * c;
  return a | (b << 1) | (c << 2) | (r << 3);
}

__device__ __forceinline__ float rfl(float x) {
  return __int_as_float(__builtin_amdgcn_readfirstlane(__float_as_int(x)));
}
#define RLg(g_, x_) __int_as_float(__builtin_amdgcn_readlane(__float_as_int(x_), (g_)))

__device__ __forceinline__ float fast_tanh(float x) {
  return 1.0f - 2.0f / (__expf(2.0f * x) + 1.0f);
}
__device__ __forceinline__ v2 sneg(v2 a) {       // i*a: (re,im)->(-im,re)
  v2 r; r.x = -a.y; r.y = a.x; return r;
}

// ===== packed complex MAC core: 4 VOP3P ops per amplitude (R16, verified) =====
__device__ __forceinline__ v2 gate_upd_p(v2 a, v2 p, v2 ar2, v2 ai2, v2 br2, v2 bi2) {
  v2 acc;
  asm("v_pk_mul_f32 %0, %1, %2" : "=v"(acc) : "v"(ar2), "v"(a));
  asm("v_pk_fma_f32 %0, %1, %2, %0 op_sel:[1,0,0] op_sel_hi:[0,1,1] neg_lo:[1,0,0]"
      : "+v"(acc) : "v"(a), "v"(ai2));
  asm("v_pk_fma_f32 %0, %1, %2, %0"
      : "+v"(acc) : "v"(p), "v"(br2));
  asm("v_pk_fma_f32 %0, %1, %2, %0 op_sel:[1,0,0] op_sel_hi:[0,1,1] neg_lo:[1,0,0]"
      : "+v"(acc) : "v"(p), "v"(bi2));
  return acc;
}
__device__ __forceinline__ v2 gate_upd_m(v2 a, v2 p, v2 ar2, v2 ai2, v2 br2, v2 bi2) {
  v2 acc;
  asm("v_pk_mul_f32 %0, %1, %2" : "=v"(acc) : "v"(ar2), "v"(a));
  asm("v_pk_fma_f32 %0, %1, %2, %0 op_sel:[1,0,0] op_sel_hi:[0,1,1] neg_hi:[1,0,0]"
      : "+v"(acc) : "v"(a), "v"(ai2));
  asm("v_pk_fma_f32 %0, %1, %2, %0 neg_lo:[1,0,0] neg_hi:[1,0,0]"
      : "+v"(acc) : "v"(p), "v"(br2));
  asm("v_pk_fma_f32 %0, %1, %2, %0 op_sel:[1,0,0] op_sel_hi:[0,1,1] neg_lo:[1,0,0]"
      : "+v"(acc) : "v"(p), "v"(bi2));
  return acc;
}

// ===== general conjugated gate (phys-space masks; LDS path only for ML>=16) =====
template<int M, int V>
__device__ __forceinline__ void gate_g(v2 (&st)[16], int lane,
                                       float ar, float ai, float br, float bi) {
  constexpr int MR = M & 15, ML = (M >> 4) & 63;
  constexpr int VR = V & 15, VL = (V >> 4) & 63;
  bool hl = false;
  if constexpr (VL != 0) hl = (__builtin_popcount(lane & VL) & 1) != 0;
  const float aiX = hl ? -ai : ai;
  const float brX = hl ? -br : br;
  v2 ar2; ar2.x = ar;  ar2.y = ar;
  v2 ai2; ai2.x = aiX; ai2.y = aiX;
  v2 br2; br2.x = brX; br2.y = brX;
  v2 bi2; bi2.x = bi;  bi2.y = bi;
  int baddr = 0;
  if constexpr (ML >= 32) baddr = (lane ^ ML) << 2;
  if constexpr (ML >= 16) {
    // LDS-path gate: batch all shuffles (partner of st[r] is shuffle of st[r^MR])
    v2 pf[16];
    #pragma unroll
    for (int r = 0; r < 16; ++r) pf[r] = xany2<ML>(st[r ^ MR], baddr);
    #pragma unroll
    for (int r = 0; r < 16; ++r) {
      if ((__builtin_popcount(r & VR) & 1) == 0)
        st[r] = gate_upd_p(st[r], pf[r], ar2, ai2, br2, bi2);
      else
        st[r] = gate_upd_m(st[r], pf[r], ar2, ai2, br2, bi2);
    }
  } else if constexpr (MR == 0) {
    #pragma unroll
    for (int r = 0; r < 16; ++r) {
      const v2 p = xany2<ML>(st[r], baddr);
      const v2 a = st[r];
      if ((__builtin_popcount(r & VR) & 1) == 0)
        st[r] = gate_upd_p(a, p, ar2, ai2, br2, bi2);
      else
        st[r] = gate_upd_m(a, p, ar2, ai2, br2, bi2);
    }
  } else {
    constexpr int HB = topbit4(MR);
    #pragma unroll
    for (int r = 0; r < 16; ++r) {
      if ((r & HB) == 0) {
        const int r1 = r ^ MR;
        v2 pa, pb;
        if constexpr (ML == 0) { pa = st[r1]; pb = st[r]; }
        else { pa = xany2<ML>(st[r1], baddr); pb = xany2<ML>(st[r], baddr); }
        const v2 a = st[r], b = st[r1];
        if ((__builtin_popcount(r & VR) & 1) == 0)
          st[r] = gate_upd_p(a, pa, ar2, ai2, br2, bi2);
        else
          st[r] = gate_upd_m(a, pa, ar2, ai2, br2, bi2);
        if ((__builtin_popcount(r1 & VR) & 1) == 0)
          st[r1] = gate_upd_p(b, pb, ar2, ai2, br2, bi2);
        else
          st[r1] = gate_upd_m(b, pb, ar2, ai2, br2, bi2);
      }
    }
  }
}

// half_ang decomposition over PHYS positions:
//  lane-lane -> Cc (lane-sign), lane-r -> dcoef[3-rbit] (lane-sign; r-sign in init),
//  r-r -> ecoef[EIDX] (both signs in init).
template<int I, int J>
__device__ __forceinline__ void pair_accum(float t, int lane, float& Cc,
                                           float (&dcf)[4], float (&ecf)[6]) {
  constexpr int pI = AA.phys[9 - I], pJ = AA.phys[9 - J];
  if constexpr (pI >= 4 && pJ >= 4) {
    const bool diff = (((lane >> (pI - 4)) ^ (lane >> (pJ - 4))) & 1) != 0;
    Cc += diff ? -t : t;
  } else if constexpr (pI >= 4 && pJ < 4) {
    const bool b = ((lane >> (pI - 4)) & 1) != 0;
    dcf[3 - pJ] += b ? -t : t;
  } else if constexpr (pI < 4 && pJ >= 4) {
    const bool b = ((lane >> (pJ - 4)) & 1) != 0;
    dcf[3 - pI] += b ? -t : t;
  } else {
    constexpr int a = (pI > pJ) ? pI : pJ;
    constexpr int b2 = (pI > pJ) ? pJ : pI;
    ecf[EIDX(a, b2)] = t;
  }
}
#define PACC(v_, i_, j_) pair_accum<i_, j_>(RLg(holder_lane45(v_), tl), lane, Cc, dcoef, ecoef);

#define GATE0(g_, q_) gate_g<(int)pmask10(1u<<(9-(q_))), (int)pmask10(1u<<(9-(q_)))>(st, lane, \
    RLg(g_,Mr00), RLg(g_,Mi00), RLg(g_,Mr01), RLg(g_,Mi01));
#define GATE1(g_, q_) gate_g<(int)pmask10(mcol(Q1i,9-(q_))), (int)pmask10(Q1.row[9-(q_)])>(st, lane, \
    RLg(g_,Mr00), RLg(g_,Mi00), RLg(g_,Mr01), RLg(g_,Mi01));
#define GATE2(g_, q_) gate_g<(int)pmask10(mcol(Q2i,9-(q_))), (int)pmask10(Q2.row[9-(q_)])>(st, lane, \
    RLg(g_,Mr00), RLg(g_,Mi00), RLg(g_,Mr01), RLg(g_,Mi01));

extern "C" __global__ void __launch_bounds__(256, 2)
qhl_kernel(const float* __restrict__ c_kt, const float* __restrict__ dc_kt,
           const float* __restrict__ vw,  const float* __restrict__ w_proj,
           const float* __restrict__ b_proj, const float* __restrict__ log_alpha,
           float* __restrict__ out) {
  const int wave = threadIdx.x >> 6;
  const int lane = threadIdx.x & 63;
  const int bid  = blockIdx.x * 4 + wave;

  const float* c   = c_kt  + (size_t)bid * 1280;
  const float* dcp = dc_kt + (size_t)bid * 1280;

  // ---- per-lane gate-matrix precompute: lane g -> gate (l=g/10, q=g%10)
  float Mr00, Mi00, Mr01, Mi01;
  {
    const int g = lane < 30 ? lane : 0;
    const int l = g / 10, q = g - l * 10;
    const float w0 = vw[g*3+0], w1 = vw[g*3+1], w2 = vw[g*3+2];
    float cY, sY; __sincosf(0.5f*w1, &sY, &cY);
    float ca, sa; __sincosf(0.5f*(w0+w2), &sa, &ca);
    float cb, sb; __sincosf(0.5f*(w0-w2), &sb, &cb);
    const float r00r =  cY*ca, r00i = -cY*sa, r01r = -sY*cb, r01i = -sY*sb;
    if (l == 0) {
      Mr00 = r00r; Mi00 = r00i; Mr01 = r01r; Mi01 = r01i;
    } else {
      const float thq = c[1270 + q], phq = dcp[1270 + q];
      float cy, sy; __sincosf(0.25f * thq, &sy, &cy);
      float cz, sz; __sincosf(0.25f * phq, &sz, &cz);
      const float e00r =  cy*cz, e00i = -cy*sz, e01r = -sy*cz, e01i =  sy*sz;
      const float e10r =  sy*cz, e10i =  sy*sz, e11r =  cy*cz, e11i =  cy*sz;
      Mr00 = r00r*e00r - r00i*e00i + r01r*e10r - r01i*e10i;
      Mi00 = r00r*e00i + r00i*e00r + r01r*e10i + r01i*e10r;
      Mr01 = r00r*e01r - r00i*e01i + r01r*e11r - r01i*e11i;
      Mi01 = r00r*e01i + r00i*e01r + r01r*e11i + r01i*e11r;
    }
  }

  // ---- correlation rows packed as (t=lane, t=lane+64) float2 pairs ----
  v2 ym[10];
  {
    const float2* c0 = (const float2*)(c   + lane * 10);
    const float2* d0 = (const float2*)(dcp + lane * 10);
    const float2* c1 = (const float2*)(c   + (lane + 64) * 10);
    const float2* d1 = (const float2*)(dcp + (lane + 64) * 10);
    #pragma unroll
    for (int k = 0; k < 5; ++k) {
      const float2 a0 = c0[k], b0 = d0[k], a1 = c1[k], b1 = d1[k];
      ym[2*k].x   = a0.x + 0.5f * b0.x;  ym[2*k].y   = a1.x + 0.5f * b1.x;
      ym[2*k+1].x = a0.y + 0.5f * b0.y;  ym[2*k+1].y = a1.y + 0.5f * b1.y;
    }
  }

  // ---- row stats via 10-value funnels ----
  {
    float mb[6];
    float m10a[10];
    #pragma unroll
    for (int k = 0; k < 10; ++k) m10a[k] = ym[k].x + ym[k].y;
    #pragma unroll
    for (int i = 0; i < 5; ++i) {
      const float send = (lane & 1) ? m10a[i] : m10a[i + 5];
      const float recv = xshfl<1>(send);
      const float keep = (lane & 1) ? m10a[i + 5] : m10a[i];
      mb[i] = keep + recv;
    }
    mb[5] = 0.0f;
    fstage<2, 3>(mb, lane);
    mb[3] = 0.0f;
    fstage<4, 2>(mb, lane);
    fstage<8, 1>(mb, lane);
    mb[0] += xshfl<16>(mb[0]);
    mb[0] += xshfl<32>(mb[0]);
    mb[0] *= (1.0f / 128.0f);
    #pragma unroll
    for (int k = 0; k < 10; ++k) {
      const float mk = RLg(holder_lane10(k), mb[0]);
      ym[k].x -= mk; ym[k].y -= mk;
    }
    float s10[10];
    #pragma unroll
    for (int k = 0; k < 10; ++k) { const v2 sq = ym[k] * ym[k]; s10[k] = sq.x + sq.y; }
    #pragma unroll
    for (int i = 0; i < 5; ++i) {
      const float send = (lane & 1) ? s10[i] : s10[i + 5];
      const float recv = xshfl<1>(send);
      const float keep = (lane & 1) ? s10[i + 5] : s10[i];
      mb[i] = keep + recv;
    }
    mb[5] = 0.0f;
    fstage<2, 3>(mb, lane);
    mb[3] = 0.0f;
    fstage<4, 2>(mb, lane);
    fstage<8, 1>(mb, lane);
    mb[0] += xshfl<16>(mb[0]);
    mb[0] += xshfl<32>(mb[0]);
    const float rsv = fminf(__builtin_amdgcn_rsqf(mb[0] * (1.0f / 127.0f)), 1e8f);
    #pragma unroll
    for (int k = 0; k < 10; ++k) {
      const float rk = RLg(holder_lane10(k), rsv);
      ym[k].x *= rk; ym[k].y *= rk;
    }
  }

  // ---- 45 pair dots via one 48-slot funnel; tanh lane-parallel ----
  const float expA = rfl(__expf(log_alpha[0]));
  float Cc = 0.0f, dcoef[4] = {0, 0, 0, 0}, ecoef[6];
  float tl;
  {
    constexpr int PI_[45] = {0,0,0,0,0,0,0,0,0, 1,1,1,1,1,1,1,1, 2,2,2,2,2,2,2,
                             3,3,3,3,3,3, 4,4,4,4,4, 5,5,5,5, 6,6,6, 7,7, 8};
    constexpr int PJ_[45] = {1,2,3,4,5,6,7,8,9, 2,3,4,5,6,7,8,9, 3,4,5,6,7,8,9,
                             4,5,6,7,8,9, 5,6,7,8,9, 6,7,8,9, 7,8,9, 8,9, 9};
    float p[48];
    #pragma unroll
    for (int v = 0; v < 45; ++v) {
      const v2 pr = ym[PI_[v]] * ym[PJ_[v]];
      p[v] = pr.x + pr.y;
    }
    p[45] = 0.0f; p[46] = 0.0f; p[47] = 0.0f;
    fstage<1, 24>(p, lane);
    fstage<2, 12>(p, lane);
    fstage<4, 6>(p, lane);
    fstage<8, 3>(p, lane);
    p[3] = 0.0f;
    fstage<16, 2>(p, lane);
    fstage<32, 1>(p, lane);
    const float sc = expA * (1.0f / 127.0f);
    tl = -1.5707963267948966f * fast_tanh(p[0] * sc);
  }
  PACC(0,0,1) PACC(1,0,2) PACC(2,0,3) PACC(3,0,4) PACC(4,0,5) PACC(5,0,6) PACC(6,0,7) PACC(7,0,8) PACC(8,0,9)
  PACC(9,1,2) PACC(10,1,3) PACC(11,1,4) PACC(12,1,5) PACC(13,1,6) PACC(14,1,7) PACC(15,1,8) PACC(16,1,9)
  PACC(17,2,3) PACC(18,2,4) PACC(19,2,5) PACC(20,2,6) PACC(21,2,7) PACC(22,2,8) PACC(23,2,9)
  PACC(24,3,4) PACC(25,3,5) PACC(26,3,6) PACC(27,3,7) PACC(28,3,8) PACC(29,3,9)
  PACC(30,4,5) PACC(31,4,6) PACC(32,4,7) PACC(33,4,8) PACC(34,4,9)
  PACC(35,5,6) PACC(36,5,7) PACC(37,5,8) PACC(38,5,9)
  PACC(39,6,7) PACC(40,6,8) PACC(41,6,9)
  PACC(42,7,8) PACC(43,7,9)
  PACC(44,8,9)

  // ---- encoding angles: wave-uniform -> SGPRs ----
  float th[10], ph[10];
  #pragma unroll
  for (int q = 0; q < 10; ++q) {
    th[q] = rfl(c[1270 + q]);
    ph[q] = rfl(dcp[1270 + q]);
  }

  // ---- per-lane R product: lane r computes R_r over the 4 register qubits ----
  float Rr_l, Ri_l;
  {
    const int rr = lane & 15;
    float prr = 1.0f, pri = 0.0f;
    #pragma unroll
    for (int qi = 0; qi < 4; ++qi) {
      const int q = RQ.q[qi];
      float cy, sy; __sincosf(0.5f * th[q], &sy, &cy);
      float cz, sz; __sincosf(0.5f * ph[q], &sz, &cz);
      const bool b = ((rr >> RQ.b[qi]) & 1) != 0;
      const float fr = b ? sy * cz : cy * cz;
      const float fi = b ? sy * sz : -cy * sz;
      const float nr = prr * fr - pri * fi;
      pri = prr * fi + pri * fr;
      prr = nr;
    }
    Rr_l = prr; Ri_l = pri;
  }

  // ---- closed-form initial state: (prod_q RZ(ph)RY(th)|0>) * e^{i h} ----
  v2 st[16];
  {
    v2 L; L.x = 1.0f; L.y = 0.0f;
    #pragma unroll
    for (int q = 0; q < 10; ++q) {
      if (QT.isl[q]) {
        float cy, sy; __sincosf(0.5f * th[q], &sy, &cy);
        float cz, sz; __sincosf(0.5f * ph[q], &sz, &cz);
        const bool b = ((lane >> QT.lb[q]) & 1) != 0;
        const float zr = b ? sy * cz : cy * cz;
        const float zi = b ? sy * sz : -cy * sz;
        L = zr * L + zi * sneg(L);
      }
    }
    #pragma unroll
    for (int r = 0; r < 16; ++r) {
      const int b3 = (r >> 3) & 1, b2 = (r >> 2) & 1, b1 = (r >> 1) & 1, b0 = r & 1;
      const float Rr = RLg(r, Rr_l);
      const float Ri = RLg(r, Ri_l);
      float h = Cc;
      h += b3 ? -dcoef[0] : dcoef[0];
      h += b2 ? -dcoef[1] : dcoef[1];
      h += b1 ? -dcoef[2] : dcoef[2];
      h += b0 ? -dcoef[3] : dcoef[3];
      h += (b3 ^ b2) ? -ecoef[0] : ecoef[0];
      h += (b3 ^ b1) ? -ecoef[1] : ecoef[1];
      h += (b3 ^ b0) ? -ecoef[2] : ecoef[2];
      h += (b2 ^ b1) ? -ecoef[3] : ecoef[3];
      h += (b2 ^ b0) ? -ecoef[4] : ecoef[4];
      h += (b1 ^ b0) ? -ecoef[5] : ecoef[5];
      float sn, cs; __sincosf(h, &sn, &cs);
      const v2 p = cs * L + sn * sneg(L);
      st[r] = Rr * p + Ri * sneg(p);
    }
  }

  // ---- layer 0 (standard frame) ----
  GATE0(0,0) GATE0(1,1) GATE0(2,2) GATE0(3,3) GATE0(4,4)
  GATE0(5,5) GATE0(6,6) GATE0(7,7) GATE0(8,8) GATE0(9,9)
  // ---- layer 1 conjugated by Q1 (CNOT block rng=1 folded) ----
  GATE1(10,0) GATE1(11,1) GATE1(12,2) GATE1(13,3) GATE1(14,4)
  GATE1(15,5) GATE1(16,6) GATE1(17,7) GATE1(18,8) GATE1(19,9)
  // ---- layer 2 conjugated by Q2 (blocks rng=1,2 folded) ----
  GATE2(20,0) GATE2(21,1) GATE2(22,2) GATE2(23,3) GATE2(24,4)
  GATE2(25,5) GATE2(26,6) GATE2(27,7) GATE2(28,8) GATE2(29,9)
  // (CNOT block rng=3 folded into measurement sign masks via Q3)

  // ---- measurement: Z expvals with Q3-row parities (phys-mapped), funnel, projection ----
  float e[10] = {0,0,0,0,0,0,0,0,0,0};
  #pragma unroll
  for (int r = 0; r < 16; ++r) {
    const v2 sq = st[r] * st[r];
    const float pp = sq.x + sq.y;
    #pragma unroll
    for (int q = 0; q < 10; ++q) {
      const bool s = (__builtin_popcount(r & (int)(pmask10(Q3.row[9-q]) & 15u)) & 1) != 0;
      e[q] += s ? -pp : pp;
    }
  }
  float mv[10];
  #pragma unroll
  for (int q = 0; q < 10; ++q) {
    const int wl = (int)((pmask10(Q3.row[9-q]) >> 4) & 63u);
    const bool sl = wl ? ((__builtin_popcount(lane & wl) & 1) != 0) : false;
    mv[q] = sl ? -e[q] : e[q];
  }
  {
    float fb[6];
    #pragma unroll
    for (int i = 0; i < 5; ++i) {
      const float send = (lane & 1) ? mv[i] : mv[i + 5];
      const float recv = xshfl<1>(send);
      const float keep = (lane & 1) ? mv[i + 5] : mv[i];
      fb[i] = keep + recv;
    }
    fb[5] = 0.0f;
    fstage<2, 3>(fb, lane);
    fb[3] = 0.0f;
    fstage<4, 2>(fb, lane);
    fstage<8, 1>(fb, lane);
    fb[0] += xshfl<16>(fb[0]);
    fb[0] += xshfl<32>(fb[0]);
    float ev[10];
    #pragma unroll
    for (int k = 0; k < 10; ++k) ev[k] = RLg(holder_lane10(k), fb[0]);
    if (lane < 3) {
      float acc = b_proj[lane];
      #pragma unroll
      for (int i = 0; i < 10; ++i) acc += w_proj[lane * 10 + i] * ev[i];
      out[(size_t)bid * 3 + lane] = acc;
    }
  }
}

extern "C" void kernel_launch(void* const* d_in, const int* in_sizes, int n_in,
                              void* d_out, int out_size, void* d_ws, size_t ws_size,
                              hipStream_t stream) {
  (void)in_sizes; (void)n_in; (void)d_ws; (void)ws_size; (void)out_size;
  const float* c_kt      = (const float*)d_in[0];
  const float* dc_kt     = (const float*)d_in[1];
  const float* vw        = (const float*)d_in[2];
  const float* w_proj    = (const float*)d_in[3];
  const float* b_proj    = (const float*)d_in[4];
  const float* log_alpha = (const float*)d_in[5];
  float* out = (float*)d_out;
  // 4096 batch elems, 1 wave each, 4 waves per 256-thread block
  qhl_kernel<<<dim3(1024), dim3(256), 0, stream>>>(c_kt, dc_kt, vw, w_proj,
                                                   b_proj, log_alpha, out);
}